// Round 1
// baseline (598.521 us; speedup 1.0000x reference)
//
#include <hip/hip_runtime.h>
#include <cstdint>
#include <cstddef>

// GNN layer, B=4, N=256, D=E=256.
// Decomposition: cat = relu(A[b,i,:] + C[b,j,:] + edges[b,i,j,:]@W_E)
//   A = nodes@W_s + b_in, C = nodes@W_e  (W_in rows: 0..255=W_s, 256..511=W_e, 512..767=W_E)
// k_main fuses: heavy GEMM (bf16 MFMA) + coef + online softmax over j + weighted sum.

typedef float f32x4 __attribute__((ext_vector_type(4)));
typedef __bf16 bf16x8 __attribute__((ext_vector_type(8)));

#define AS1 __attribute__((address_space(1)))
#define AS3 __attribute__((address_space(3)))

__device__ __forceinline__ void async_cp16(const void* g, void* l) {
  __builtin_amdgcn_global_load_lds((const AS1 void*)g, (AS3 void*)l, 16, 0, 0);
}

// ---------------- k_pack: W_E -> bf16, B-fragment-friendly layout ----------------
// W_p[(kb8*256 + c)*8 + e] = bf16(W_in[(512 + kb8*8 + e)*256 + c]), kb8=0..31, c=0..255
__global__ __launch_bounds__(256) void k_pack(const float* __restrict__ W_in,
                                              __bf16* __restrict__ W_p) {
  int idx = blockIdx.x * 256 + threadIdx.x;   // 32 blocks -> 8192 = 32*256
  int kb8 = idx >> 8;
  int c = idx & 255;
  bf16x8 v;
#pragma unroll
  for (int e = 0; e < 8; ++e) v[e] = (__bf16)W_in[(size_t)(512 + kb8 * 8 + e) * 256 + c];
  *reinterpret_cast<bf16x8*>(W_p + (size_t)idx * 8) = v;
}

// ---------------- k_ac: A = nodes@W_s + b_in ; C = nodes@W_e  (f32) ----------------
__global__ __launch_bounds__(256) void k_ac(const float* __restrict__ nodes,
                                            const float* __restrict__ W_in,
                                            const float* __restrict__ b_in,
                                            float* __restrict__ A, float* __restrict__ C) {
  __shared__ float nd[4][256];
  const int t = threadIdx.x;
  const int row0 = blockIdx.x * 4;           // 256 blocks x 4 rows = 1024 = B*N
#pragma unroll
  for (int r = 0; r < 4; ++r) nd[r][t] = nodes[(size_t)(row0 + r) * 256 + t];
  __syncthreads();
  float accA[4] = {0.f, 0.f, 0.f, 0.f}, accC[4] = {0.f, 0.f, 0.f, 0.f};
#pragma unroll 4
  for (int k = 0; k < 256; ++k) {
    float ws_ = W_in[(size_t)k * 256 + t];
    float we_ = W_in[(size_t)(256 + k) * 256 + t];
#pragma unroll
    for (int r = 0; r < 4; ++r) {
      accA[r] += nd[r][k] * ws_;
      accC[r] += nd[r][k] * we_;
    }
  }
  float bi = b_in[t];
#pragma unroll
  for (int r = 0; r < 4; ++r) {
    A[(size_t)(row0 + r) * 256 + t] = accA[r] + bi;
    C[(size_t)(row0 + r) * 256 + t] = accC[r];
  }
}

// ---------------- k_main: fused heavy GEMM + softmax + weighted sum ----------------
// grid = B*N blocks (one per (b,i)), 256 threads = 4 waves.
// Per j-tile (64 rows): stage edges tile (64x256 f32, XOR-swizzled) -> MFMA 64x256x256
// -> +A +C, relu -> store cat -> coef -> online softmax -> accumulate r.
__global__ __launch_bounds__(256, 2) void k_main(
    const float* __restrict__ edges, const float* __restrict__ aux,
    const float* __restrict__ A, const float* __restrict__ C,
    const __bf16* __restrict__ W_p, const float* __restrict__ W_coef,
    const float* __restrict__ b_coef, float* __restrict__ out_cat,
    float* __restrict__ resid) {
  __shared__ float ET[64 * 256];     // 64 KB, 16B-chunk index XOR-swizzled by (row&7)
  __shared__ float coef_l[64];
  __shared__ float w_lds[64];

  const int tid = threadIdx.x;
  const int lane = tid & 63;
  const int wv = tid >> 6;
  const int l15 = lane & 15;
  const int lg = lane >> 4;
  const int bi = blockIdx.x;          // b*N + i
  const int b = bi >> 8;

  const f32x4 vzero = {0.f, 0.f, 0.f, 0.f};

  // per-lane column weights for this wave: d = wv*64 + nc*16 + l15
  float pA[4], wc[4];
#pragma unroll
  for (int nc = 0; nc < 4; ++nc) {
    int d = wv * 64 + nc * 16 + l15;
    pA[nc] = A[(size_t)bi * 256 + d];
    wc[nc] = W_coef[d];
  }
  const float bcoef = b_coef[0];

  const float* eg_base = edges + (size_t)bi * (256 * 256);
  float* cat_base = out_cat + (size_t)bi * (256 * 256);

  float m_run = -INFINITY, l_run = 0.f;
  float r_lane[4] = {0.f, 0.f, 0.f, 0.f};
  f32x4 acc[4][4];

  for (int jt = 0; jt < 4; ++jt) {
    const int j0 = jt * 64;
    if (tid < 64) coef_l[tid] = 0.f;

    // ---- stage edges[b,i,j0..j0+63,:] into LDS (swizzled), 4096 16B chunks ----
    {
      const char* gB = (const char*)(eg_base + (size_t)j0 * 256);
#pragma unroll
      for (int it = 0; it < 16; ++it) {
        int q = it * 256 + tid;               // chunk index in tile
        int row = q >> 6, cc = q & 63;
        int gchunk = (row << 6) | (cc ^ (row & 7));  // inverse-swizzled source
        char* dst = (char*)ET + (size_t)(it * 256 + (tid & ~63)) * 16; // wave-uniform base
        async_cp16(gB + (size_t)gchunk * 16, dst);
      }
    }
    asm volatile("s_waitcnt vmcnt(0)" ::: "memory");
    __syncthreads();

    // ---- GEMM: 64(j) x 256(d) x 256(k), this wave: cols wv*64..wv*64+63 ----
#pragma unroll
    for (int mr = 0; mr < 4; ++mr)
#pragma unroll
      for (int nc = 0; nc < 4; ++nc) acc[mr][nc] = vzero;

    const f32x4* ET4 = (const f32x4*)ET;
#pragma unroll 1
    for (int ks = 0; ks < 8; ++ks) {
      bf16x8 bfr[4];
#pragma unroll
      for (int nc = 0; nc < 4; ++nc) {
        int col = wv * 64 + nc * 16 + l15;
        int kb8 = ks * 4 + lg;
        bfr[nc] = *reinterpret_cast<const bf16x8*>(W_p + ((size_t)kb8 * 256 + col) * 8);
      }
#pragma unroll
      for (int mr = 0; mr < 4; ++mr) {
        int arow = mr * 16 + l15;
        int kc = ks * 8 + lg * 2;
        int sw = arow & 7;
        f32x4 fa = ET4[arow * 64 + (kc ^ sw)];
        f32x4 fb = ET4[arow * 64 + ((kc + 1) ^ sw)];
        bf16x8 af;
#pragma unroll
        for (int e = 0; e < 4; ++e) {
          af[e] = (__bf16)fa[e];
          af[4 + e] = (__bf16)fb[e];
        }
#pragma unroll
        for (int nc = 0; nc < 4; ++nc)
          acc[mr][nc] = __builtin_amdgcn_mfma_f32_16x16x32_bf16(af, bfr[nc], acc[mr][nc], 0, 0, 0);
      }
    }

    // ---- epilogue: +A +C, relu, store cat, coef partial sums ----
#pragma unroll
    for (int mr = 0; mr < 4; ++mr) {
#pragma unroll
      for (int r = 0; r < 4; ++r) {
        int jl = mr * 16 + lg * 4 + r;        // local j in tile
        int j = j0 + jl;
        const float* Crow = C + ((size_t)(b * 256 + j)) * 256;
        float cp = 0.f;
#pragma unroll
        for (int nc = 0; nc < 4; ++nc) {
          int d = wv * 64 + nc * 16 + l15;
          float pre = acc[mr][nc][r] + pA[nc] + Crow[d];
          float cv = fmaxf(pre, 0.f);
          acc[mr][nc][r] = cv;                // keep cat in regs for weighted sum
          cat_base[(size_t)j * 256 + d] = cv;
          cp += cv * wc[nc];
        }
        cp += __shfl_xor(cp, 1);
        cp += __shfl_xor(cp, 2);
        cp += __shfl_xor(cp, 4);
        cp += __shfl_xor(cp, 8);
        if (l15 == 0) atomicAdd(&coef_l[jl], cp);
      }
    }
    __syncthreads();

    // ---- online softmax over this tile (redundant per wave, identical results) ----
    float sc = coef_l[lane] + aux[(size_t)bi * 256 + j0 + lane] + bcoef;
    float mt = sc;
#pragma unroll
    for (int mm = 1; mm < 64; mm <<= 1) mt = fmaxf(mt, __shfl_xor(mt, mm));
    float mnew = fmaxf(m_run, mt);
    float scalef = __expf(m_run - mnew);      // first tile: exp(-inf)=0
    float wgt = __expf(sc - mnew);
    float st = wgt;
#pragma unroll
    for (int mm = 1; mm < 64; mm <<= 1) st += __shfl_xor(st, mm);
    l_run = l_run * scalef + st;
    m_run = mnew;
    if (tid < 64) w_lds[tid] = wgt;
    __syncthreads();

    // ---- accumulate r += wgt[j] * cat[j,d] (per-lane partial over its 16 j's) ----
#pragma unroll
    for (int nc = 0; nc < 4; ++nc) r_lane[nc] *= scalef;
#pragma unroll
    for (int mr = 0; mr < 4; ++mr) {
#pragma unroll
      for (int r = 0; r < 4; ++r) {
        float wj = w_lds[mr * 16 + lg * 4 + r];
#pragma unroll
        for (int nc = 0; nc < 4; ++nc) r_lane[nc] += wj * acc[mr][nc][r];
      }
    }
  }

  // ---- finalize residuals: reduce partials across the 4 row-groups ----
#pragma unroll
  for (int nc = 0; nc < 4; ++nc) {
    float r = r_lane[nc];
    r += __shfl_xor(r, 16);
    r += __shfl_xor(r, 32);
    if (lg == 0) resid[(size_t)bi * 256 + wv * 64 + nc * 16 + l15] = r / l_run;
  }
}

// ---------------- k_out: nodes_out = nodes + relu(resid@W_out + b_out) ----------------
__global__ __launch_bounds__(256) void k_out(const float* __restrict__ nodes,
                                             const float* __restrict__ resid,
                                             const float* __restrict__ W_out,
                                             const float* __restrict__ b_out,
                                             float* __restrict__ out_nodes) {
  __shared__ float rs[4][256];
  const int t = threadIdx.x;
  const int row0 = blockIdx.x * 4;
#pragma unroll
  for (int r = 0; r < 4; ++r) rs[r][t] = resid[(size_t)(row0 + r) * 256 + t];
  __syncthreads();
  float acc[4] = {0.f, 0.f, 0.f, 0.f};
#pragma unroll 4
  for (int k = 0; k < 256; ++k) {
    float wv_ = W_out[(size_t)k * 256 + t];
#pragma unroll
    for (int r = 0; r < 4; ++r) acc[r] += rs[r][k] * wv_;
  }
  float bo = b_out[t];
#pragma unroll
  for (int r = 0; r < 4; ++r) {
    out_nodes[(size_t)(row0 + r) * 256 + t] =
        nodes[(size_t)(row0 + r) * 256 + t] + fmaxf(acc[r] + bo, 0.f);
  }
}

extern "C" void kernel_launch(void* const* d_in, const int* in_sizes, int n_in,
                              void* d_out, int out_size, void* d_ws, size_t ws_size,
                              hipStream_t stream) {
  const float* nodes = (const float*)d_in[0];
  const float* edges = (const float*)d_in[1];
  const float* aux = (const float*)d_in[2];
  // d_in[3] = nums (int, ==256), unused
  const float* W_in = (const float*)d_in[4];
  const float* b_in = (const float*)d_in[5];
  const float* W_coef = (const float*)d_in[6];
  const float* b_coef = (const float*)d_in[7];
  const float* W_out = (const float*)d_in[8];
  const float* b_out = (const float*)d_in[9];

  float* out_nodes = (float*)d_out;                  // [B,N,D] = 262144
  float* out_cat = out_nodes + 4 * 256 * 256;        // [B,N,N,D]

  // workspace: A (1MB) | C (1MB) | resid (1MB) | W_p bf16 (128KB)
  float* A = (float*)d_ws;
  float* Cm = A + 4 * 256 * 256;
  float* resid = Cm + 4 * 256 * 256;
  __bf16* W_p = (__bf16*)(resid + 4 * 256 * 256);

  k_pack<<<dim3(32), dim3(256), 0, stream>>>(W_in, W_p);
  k_ac<<<dim3(256), dim3(256), 0, stream>>>(nodes, W_in, b_in, A, Cm);
  k_main<<<dim3(1024), dim3(256), 0, stream>>>(edges, aux, A, Cm, W_p, W_coef, b_coef,
                                               out_cat, resid);
  k_out<<<dim3(256), dim3(256), 0, stream>>>(nodes, resid, W_out, b_out, out_nodes);
}